// Round 3
// baseline (1537.044 us; speedup 1.0000x reference)
//
#include <hip/hip_runtime.h>
#include <hip/hip_bf16.h>

typedef unsigned int u32;
typedef unsigned short u16;

#define B_ 64
#define N_ 8192
#define DI 8
#define O_ 10
#define DO_ 16
#define OD 160          // O_*DO_
#define NCHUNK 32       // n per block; grid = N_/NCHUNK = 256 blocks
#define SROW 161        // padded fp32 row stride for s_lds (odd -> 2 lanes/bank, free)
#define VROW 162        // padded u16 row stride for v_lds (dword stride 81, odd)

static __device__ __forceinline__ float blo(u32 p) {
    return __uint_as_float(p << 16);
}
static __device__ __forceinline__ float bhi(u32 p) {
    return __uint_as_float(p & 0xFFFF0000u);
}

// PHASE 0: c = 0.1 uniform (softmax of zeros), accumulate 0.1*u_hat into S.
// PHASE 1: t[o] = sum_d u_hat*v, softmax over o, accumulate c[o]*u_hat into S.
//          (used for routing rounds 1 and 2; v = v0, then v0+v1 since
//           b2 = b1 + u.v1 = u.(v0+v1) -- no b_ij storage needed)
template <int PHASE>
__global__ __launch_bounds__(1024, 4)
void caps_pass(const float* __restrict__ Xf, const float* __restrict__ Wf,
               const u16* __restrict__ Vb, float* __restrict__ Sout) {
    __shared__ float s_lds[B_ * SROW];
    __shared__ u16 v_lds[B_ * VROW];

    const int tid = threadIdx.x;
    for (int i = tid; i < B_ * SROW; i += 1024) s_lds[i] = 0.0f;
    if (PHASE > 0) {
        for (int i = tid; i < B_ * OD; i += 1024) {
            int b = i / OD, od = i - b * OD;
            v_lds[b * VROW + od] = Vb[i];
        }
    }
    __syncthreads();

    const int b = tid & 63;                                   // lane = batch index
    const int w = __builtin_amdgcn_readfirstlane(tid >> 6);   // wave id 0..15 (uniform)

    #pragma unroll 1
    for (int k = 0; k < NCHUNK / 16; ++k) {
        const int n = blockIdx.x * NCHUNK + w + 16 * k;       // wave-uniform n

        // x[b][n][0..7]: 8 fp32 = 32 B per lane (two float4 loads)
        const float4 x0 = *(const float4*)(Xf + ((size_t)b * N_ + n) * DI);
        const float4 x1 = *(const float4*)(Xf + ((size_t)b * N_ + n) * DI + 4);
        float xf[8];
        xf[0] = x0.x; xf[1] = x0.y; xf[2] = x0.z; xf[3] = x0.w;
        xf[4] = x1.x; xf[5] = x1.y; xf[6] = x1.z; xf[7] = x1.w;

        // W[n][o][d][i] row base: wave-uniform -> scalar loads (SGPR operand FMAs)
        const float* wrow = Wf + (size_t)n * (O_ * DO_ * DI);

        if (PHASE == 0) {
            #pragma unroll
            for (int o = 0; o < O_; ++o) {
                #pragma unroll
                for (int d = 0; d < DO_; ++d) {
                    const float* wp = wrow + (o * DO_ + d) * DI;
                    float u = 0.0f;
                    #pragma unroll
                    for (int ii = 0; ii < DI; ++ii) u = fmaf(wp[ii], xf[ii], u);
                    atomicAdd(&s_lds[b * SROW + o * DO_ + d], 0.1f * u);
                }
            }
        } else {
            // ---- loop 1: agreement logits t[o] = sum_d u_hat[o,d]*v[b,o,d]
            float t[O_];
            #pragma unroll
            for (int o = 0; o < O_; ++o) {
                float acc = 0.0f;
                #pragma unroll
                for (int d2 = 0; d2 < 8; ++d2) {
                    const int d0 = 2 * d2;
                    const float* wp = wrow + (o * DO_ + d0) * DI;
                    float u0 = 0.0f, u1 = 0.0f;
                    #pragma unroll
                    for (int ii = 0; ii < DI; ++ii) {
                        u0 = fmaf(wp[ii], xf[ii], u0);
                        u1 = fmaf(wp[DI + ii], xf[ii], u1);
                    }
                    const u32 vv = *(const u32*)&v_lds[b * VROW + o * DO_ + d0];
                    acc = fmaf(u0, blo(vv), acc);
                    acc = fmaf(u1, bhi(vv), acc);
                }
                t[o] = acc;
            }
            // ---- softmax over the 10 out-capsules (|t| small, no max-sub needed)
            float e[O_], den = 0.0f;
            #pragma unroll
            for (int o = 0; o < O_; ++o) { e[o] = __expf(t[o]); den += e[o]; }
            const float rinv = 1.0f / den;
            // ---- loop 2: recompute u_hat, accumulate c[o]*u_hat into LDS s
            #pragma unroll
            for (int o = 0; o < O_; ++o) {
                const float c = e[o] * rinv;
                #pragma unroll
                for (int d = 0; d < DO_; ++d) {
                    const float* wp = wrow + (o * DO_ + d) * DI;
                    float u = 0.0f;
                    #pragma unroll
                    for (int ii = 0; ii < DI; ++ii) u = fmaf(wp[ii], xf[ii], u);
                    atomicAdd(&s_lds[b * SROW + o * DO_ + d], c * u);
                }
            }
        }
    }
    __syncthreads();
    // block-level partial -> global accumulator
    for (int i = tid; i < B_ * OD; i += 1024) {
        int bb = i / OD, od = i - bb * OD;
        atomicAdd(&Sout[i], s_lds[bb * SROW + od]);
    }
}

// squash: norm over the OUT-CAPSULE axis (faithful to reference!), per (b,d).
// PHASE 0: v0 = squash(S); store fp32 v0 and bf16 v0; zero S.
// PHASE 1: v1 = squash(S); store bf16 (v0+v1); zero S.
// PHASE 2: out = fp32 squash(S)  (reference output dtype is float32).
template <int PHASE>
__global__ __launch_bounds__(1024)
void caps_finalize(float* __restrict__ S, float* __restrict__ V0f,
                   u16* __restrict__ Vb, float* __restrict__ out) {
    const int tid = threadIdx.x;      // 1024 = 64 b * 16 d
    const int b = tid >> 4, d = tid & 15;
    float sv[O_];
    float norm = 0.0f;
    #pragma unroll
    for (int o = 0; o < O_; ++o) {
        sv[o] = S[b * OD + o * DO_ + d];
        norm = fmaf(sv[o], sv[o], norm);
    }
    const float scale = norm / (1.0f + norm) * rsqrtf(norm + 1e-9f);
    #pragma unroll
    for (int o = 0; o < O_; ++o) {
        const int idx = b * OD + o * DO_ + d;
        const float v = scale * sv[o];
        if (PHASE == 0) {
            V0f[idx] = v;
            __hip_bfloat16 h = __float2bfloat16(v);
            Vb[idx] = *(const u16*)&h;
            S[idx] = 0.0f;
        } else if (PHASE == 1) {
            const float vs = V0f[idx] + v;
            __hip_bfloat16 h = __float2bfloat16(vs);
            Vb[idx] = *(const u16*)&h;
            S[idx] = 0.0f;
        } else {
            out[idx] = v;
        }
    }
}

extern "C" void kernel_launch(void* const* d_in, const int* in_sizes, int n_in,
                              void* d_out, int out_size, void* d_ws, size_t ws_size,
                              hipStream_t stream) {
    const float* Xf = (const float*)d_in[0];   // x: [64, 8192, 8] fp32
    const float* Wf = (const float*)d_in[1];   // W: [1, 8192, 10, 16, 8] fp32

    float* S = (float*)d_ws;               // 10240 fp32 accumulator
    float* V0f = S + B_ * OD;              // 10240 fp32 (v0)
    u16* Vb = (u16*)(V0f + B_ * OD);       // 10240 bf16 (v for next pass)
    float* out = (float*)d_out;

    const dim3 grid(N_ / NCHUNK), blk(1024), one(1);

    hipMemsetAsync(S, 0, B_ * OD * sizeof(float), stream);

    // routing round 0: c = 0.1 uniform
    caps_pass<0><<<grid, blk, 0, stream>>>(Xf, Wf, nullptr, S);
    caps_finalize<0><<<one, blk, 0, stream>>>(S, V0f, Vb, nullptr);

    // routing round 1: logits = u.v0
    caps_pass<1><<<grid, blk, 0, stream>>>(Xf, Wf, Vb, S);
    caps_finalize<1><<<one, blk, 0, stream>>>(S, V0f, Vb, nullptr);

    // routing round 2: logits = u.(v0+v1)
    caps_pass<1><<<grid, blk, 0, stream>>>(Xf, Wf, Vb, S);
    caps_finalize<2><<<one, blk, 0, stream>>>(S, nullptr, nullptr, out);
}